// Round 1
// baseline (841.356 us; speedup 1.0000x reference)
//
#include <hip/hip_runtime.h>
#include <hip/hip_bf16.h>

// LieNet: h = relu(src@Wm+bm); tmp = relu(cat(h[s],h[s+1])@Wb+bb); out = cumsum_s(h[:-1]+tmp)
// S=2048, B=256, D=128. All fp32 in/out; internal GEMMs in bf16 MFMA (fp32 acc).
//
// Workspace layout (needs ~136.5 MB):
//   [0, 134217728)               h as bf16, [S=2048][B=256][D=128]
//   [134217728, 136314880)       segsum fp32, [16][32768]
//   [136314880, 136347648)       Wm swizzled bf16 (16384 elems)
//   [136347648, 136413184)       Wb swizzled bf16 (32768 elems, two 128-halves)

#define S_DIM 2048
#define B_DIM 256
#define D_DIM 128
#define SM1   2047
#define NCOL  (B_DIM * D_DIM)   // 32768
#define NSEG  16
#define SEGLEN 128              // 16*128 = 2048 >= 2047

typedef __attribute__((ext_vector_type(8))) short bf16x8;
typedef __attribute__((ext_vector_type(4))) float f32x4;

__device__ inline short f2bf(float x) {
    unsigned u = __builtin_bit_cast(unsigned, x);
    unsigned r = (u + 0x7fffu + ((u >> 16) & 1u)) >> 16;
    return (short)r;
}
__device__ inline float bf2f(short v) {
    unsigned u = ((unsigned)(unsigned short)v) << 16;
    return __builtin_bit_cast(float, u);
}

// ---------------- K0: swizzle weights into MFMA B-fragment order ----------------
// B-fragment for mfma_f32_16x16x32_bf16: lane holds B[k=quad*8+j][n=(lane&15)],
// j=0..7. Swizzled index: ((n_tile*4 + kt)*64 + lane)*8 + j.
__global__ __launch_bounds__(256) void k0_prep(const float* __restrict__ Wm,
                                               const float* __restrict__ Wb,
                                               short* __restrict__ Wm_sw,
                                               short* __restrict__ Wb_sw) {
    int idx = blockIdx.x * 256 + threadIdx.x;
    if (idx < 16384) {
        int j = idx & 7, lane = (idx >> 3) & 63, kt = (idx >> 9) & 3, nt = idx >> 11;
        int k = kt * 32 + ((lane >> 4) << 3) + j;
        int n = nt * 16 + (lane & 15);
        Wm_sw[idx] = f2bf(Wm[k * D_DIM + n]);
    }
    if (idx < 32768) {
        int half = idx >> 14;
        int r = idx & 16383;
        int j = r & 7, lane = (r >> 3) & 63, kt = (r >> 9) & 3, nt = r >> 11;
        int k = kt * 32 + ((lane >> 4) << 3) + j;
        int n = nt * 16 + (lane & 15);
        Wb_sw[idx] = f2bf(Wb[(half * 128 + k) * D_DIM + n]);
    }
}

// ---------------- K1: h = relu(src @ Wm + bm), bf16 out ----------------
// One block = 4 waves * 16 rows = 64 rows of the [S*B, 128] GEMM, all N=128.
__global__ __launch_bounds__(256, 4) void k1_h(const float* __restrict__ src,
                                               const short* __restrict__ Wm_sw,
                                               const float* __restrict__ bm,
                                               short* __restrict__ h) {
    const int lane = threadIdx.x & 63;
    const int wave = threadIdx.x >> 6;
    const int m = lane & 15;
    const int quad = lane >> 4;
    const int rowBase = blockIdx.x * 64 + wave * 16;

    const float* arow = src + (size_t)(rowBase + m) * D_DIM + quad * 8;

    f32x4 acc[8];
#pragma unroll
    for (int n = 0; n < 8; ++n) acc[n] = (f32x4){0.f, 0.f, 0.f, 0.f};

#pragma unroll
    for (int kt = 0; kt < 4; ++kt) {
        float av[8];
        *(float4*)(av)     = *(const float4*)(arow + kt * 32);
        *(float4*)(av + 4) = *(const float4*)(arow + kt * 32 + 4);
        bf16x8 a;
#pragma unroll
        for (int j = 0; j < 8; ++j) a[j] = f2bf(av[j]);
#pragma unroll
        for (int n = 0; n < 8; ++n) {
            bf16x8 b = *(const bf16x8*)(Wm_sw + ((size_t)(n * 4 + kt) * 64 + lane) * 8);
            acc[n] = __builtin_amdgcn_mfma_f32_16x16x32_bf16(a, b, acc[n], 0, 0, 0);
        }
    }

    // C/D layout: col = lane&15, row = quad*4 + reg
    short* hout = h + (size_t)(rowBase + quad * 4) * D_DIM;
#pragma unroll
    for (int n = 0; n < 8; ++n) {
        int col = n * 16 + m;
        float bias = bm[col];
#pragma unroll
        for (int i = 0; i < 4; ++i) {
            float v = acc[n][i] + bias;
            v = v > 0.f ? v : 0.f;
            hout[(size_t)i * D_DIM + col] = f2bf(v);
        }
    }
}

// ---------------- K2: g = relu(h[s]@Wb0 + h[s+1]@Wb1 + bb) + h[s]  (fp32 -> d_out) ----------------
// blockIdx: s = bid>>2, b-tile = (bid&3)*64. 2047*4 blocks.
__global__ __launch_bounds__(256, 4) void k2_g(const short* __restrict__ h,
                                               const short* __restrict__ Wb_sw,
                                               const float* __restrict__ bb,
                                               float* __restrict__ g) {
    const int lane = threadIdx.x & 63;
    const int wave = threadIdx.x >> 6;
    const int m = lane & 15;
    const int quad = lane >> 4;
    const int s = blockIdx.x >> 2;
    const int bBase = (blockIdx.x & 3) * 64 + wave * 16;

    const short* h0 = h + ((size_t)s * B_DIM + bBase + m) * D_DIM + quad * 8;
    const short* h1 = h0 + (size_t)B_DIM * D_DIM;

    f32x4 acc[8];
#pragma unroll
    for (int n = 0; n < 8; ++n) acc[n] = (f32x4){0.f, 0.f, 0.f, 0.f};

#pragma unroll
    for (int kt = 0; kt < 4; ++kt) {
        bf16x8 a = *(const bf16x8*)(h0 + kt * 32);
#pragma unroll
        for (int n = 0; n < 8; ++n) {
            bf16x8 b = *(const bf16x8*)(Wb_sw + ((size_t)(n * 4 + kt) * 64 + lane) * 8);
            acc[n] = __builtin_amdgcn_mfma_f32_16x16x32_bf16(a, b, acc[n], 0, 0, 0);
        }
    }
#pragma unroll
    for (int kt = 0; kt < 4; ++kt) {
        bf16x8 a = *(const bf16x8*)(h1 + kt * 32);
#pragma unroll
        for (int n = 0; n < 8; ++n) {
            bf16x8 b = *(const bf16x8*)(Wb_sw + 16384 + ((size_t)(n * 4 + kt) * 64 + lane) * 8);
            acc[n] = __builtin_amdgcn_mfma_f32_16x16x32_bf16(a, b, acc[n], 0, 0, 0);
        }
    }

    const short* hrow = h + ((size_t)s * B_DIM + bBase + quad * 4) * D_DIM;
    float* grow = g + ((size_t)s * B_DIM + bBase + quad * 4) * D_DIM;
#pragma unroll
    for (int n = 0; n < 8; ++n) {
        int col = n * 16 + m;
        float bias = bb[col];
#pragma unroll
        for (int i = 0; i < 4; ++i) {
            float v = acc[n][i] + bias;
            v = v > 0.f ? v : 0.f;
            v += bf2f(hrow[(size_t)i * D_DIM + col]);
            grow[(size_t)i * D_DIM + col] = v;
        }
    }
}

// ---------------- K3: per-segment column sums ----------------
__global__ __launch_bounds__(256) void k3_segsum(const float* __restrict__ g,
                                                 float* __restrict__ segsum) {
    int t = blockIdx.x * 256 + threadIdx.x;   // 0 .. 16*32768-1
    int col = t & (NCOL - 1);
    int seg = t >> 15;
    int s0 = seg * SEGLEN;
    int send = min(s0 + SEGLEN, SM1);
    float acc = 0.f;
    for (int s = s0; s < send; ++s) acc += g[(size_t)s * NCOL + col];
    segsum[(size_t)seg * NCOL + col] = acc;
}

// ---------------- K4: in-place segmented cumsum with segment offsets ----------------
__global__ __launch_bounds__(256) void k4_scan(float* __restrict__ g,
                                               const float* __restrict__ segsum) {
    int t = blockIdx.x * 256 + threadIdx.x;
    int col = t & (NCOL - 1);
    int seg = t >> 15;
    int s0 = seg * SEGLEN;
    int send = min(s0 + SEGLEN, SM1);
    float acc = 0.f;
    for (int j = 0; j < seg; ++j) acc += segsum[(size_t)j * NCOL + col];
    for (int s = s0; s < send; ++s) {
        acc += g[(size_t)s * NCOL + col];
        g[(size_t)s * NCOL + col] = acc;
    }
}

extern "C" void kernel_launch(void* const* d_in, const int* in_sizes, int n_in,
                              void* d_out, int out_size, void* d_ws, size_t ws_size,
                              hipStream_t stream) {
    const float* src = (const float*)d_in[0];
    const float* Wm  = (const float*)d_in[1];
    const float* bm  = (const float*)d_in[2];
    const float* Wb  = (const float*)d_in[3];
    const float* bb  = (const float*)d_in[4];
    float* out = (float*)d_out;

    char* ws = (char*)d_ws;
    short* h       = (short*)(ws);
    float* segsum  = (float*)(ws + 134217728ull);
    short* Wm_sw   = (short*)(ws + 136314880ull);
    short* Wb_sw   = (short*)(ws + 136347648ull);

    hipLaunchKernelGGL(k0_prep, dim3(128), dim3(256), 0, stream, Wm, Wb, Wm_sw, Wb_sw);
    hipLaunchKernelGGL(k1_h, dim3((S_DIM * B_DIM) / 64), dim3(256), 0, stream, src, Wm_sw, bm, h);
    hipLaunchKernelGGL(k2_g, dim3(SM1 * 4), dim3(256), 0, stream, h, Wb_sw, bb, out);
    hipLaunchKernelGGL(k3_segsum, dim3((NSEG * NCOL) / 256), dim3(256), 0, stream, out, segsum);
    hipLaunchKernelGGL(k4_scan, dim3((NSEG * NCOL) / 256), dim3(256), 0, stream, out, segsum);
}